// Round 8
// baseline (812.528 us; speedup 1.0000x reference)
//
#include <hip/hip_runtime.h>
#include <hip/hip_cooperative_groups.h>
#include <stdint.h>

namespace cg = cooperative_groups;

// Problem constants
constexpr int B_ = 8, N_ = 4096, E_ = 2048, C_ = 128;
constexpr int CN = 144;   // 128 channels + 1 ones-col + 15 pad
constexpr int KT = 32;    // K per MFMA step
constexpr int MT = 32;    // M rows per virtual block (2 x 16-row groups)
constexpr int NWK = 4;    // K-split across the 4 waves of a wave-group
constexpr int LRF = 145;  // reduction LDS row stride (floats)
constexpr int GR  = 2 * 32 * LRF;   // per-wave-group reduction floats

typedef short bf16x8 __attribute__((ext_vector_type(8)));
typedef float f32x4  __attribute__((ext_vector_type(4)));

__device__ inline uint16_t bf16_rne(float f) {
    uint32_t u = __builtin_bit_cast(uint32_t, f);
    return (uint16_t)((u + 0x7FFFu + ((u >> 16) & 1u)) >> 16);
}

constexpr size_t HT_E  = (size_t)B_ * (N_ / 32) * E_;  // 2M dwords = 8 MB
constexpr size_t WT_E  = (size_t)CN * C_;
constexpr size_t EBF_E = (size_t)B_ * CN * E_;

// ---------------------------------------------------------------------------
// One virtual GEMM block: 4 waves (one wave-group) K-split a 32-row M-tile.
// Barrier-free main loop (per-lane A from bit words, per-lane b128 B loads),
// 3-barrier LDS reduction, wave0 epilogue. No early returns (coop-safe).
//  MODE 0 (fc) : A = x fp32,    B = WTb,  out bf16 C^T xwbT (+bias)
//  MODE 1 (v2e): A = H^T bits,  B = xwbT, out bf16 C^T ebfT (x 1/s_e)
//  MODE 2 (e2v): A = H bits,    B = ebfT, out fp32 row-major (x 1/d_n)
// ---------------------------------------------------------------------------
template <int MODE>
__device__ __forceinline__ void gemm_block(
        int vb, int tg, float* __restrict__ R,
        const float* __restrict__ Ax, const uint32_t* __restrict__ HTp,
        const uint16_t* __restrict__ Btb, const float* __restrict__ bias,
        uint16_t* __restrict__ outT, float* __restrict__ outF) {
    constexpr int K  = (MODE == 0) ? C_ : (MODE == 1) ? N_ : E_;
    constexpr int KW = K / NWK;
    constexpr int SW = KW / KT;                 // 1 / 32 / 16
    constexpr size_t BBS = (MODE == 0) ? 0 : (size_t)CN * K;
    constexpr int OLD = (MODE == 0) ? N_ : E_;

    const int wave = tg >> 6, lane = tg & 63;
    const int l15 = lane & 15, quad = lane >> 4;
    const int batch = vb & 7;
    const int m0 = (vb >> 3) * MT;
    const int kwv = wave * KW;

    const uint16_t* Bp = Btb + (size_t)batch * BBS;
    const uint32_t* Hp = HTp + (size_t)batch * (N_ / 32) * E_;

    f32x4 acc[18];
#pragma unroll
    for (int i = 0; i < 18; ++i) acc[i] = (f32x4){0.f, 0.f, 0.f, 0.f};

    // double-buffered operand regs — indexed ONLY with literal 0/1
    float    af0[16], af1[16];      // MODE 0
    uint32_t aw0[2], aw1_[2];       // MODE 1
    uint4    ax0[2], ax1[2];        // MODE 2
    bf16x8   bf0[9], bf1[9];

    auto loadA = [&](int k0, int buf) __attribute__((always_inline)) {
        if constexpr (MODE == 0) {
            float* dst = buf ? af1 : af0;
#pragma unroll
            for (int g = 0; g < 2; ++g) {
                const float* ap = Ax + ((size_t)batch * N_ + m0 + g * 16 + l15) * C_ + k0 + quad * 8;
                const float4 f0 = *(const float4*)ap;
                const float4 f1 = *(const float4*)(ap + 4);
                dst[g * 8 + 0] = f0.x; dst[g * 8 + 1] = f0.y; dst[g * 8 + 2] = f0.z; dst[g * 8 + 3] = f0.w;
                dst[g * 8 + 4] = f1.x; dst[g * 8 + 5] = f1.y; dst[g * 8 + 6] = f1.z; dst[g * 8 + 7] = f1.w;
            }
        } else if constexpr (MODE == 1) {
            uint32_t* dst = buf ? aw1_ : aw0;
            const uint32_t* p = Hp + (size_t)(k0 >> 5) * E_ + m0 + l15;
            dst[0] = p[0];
            dst[1] = p[16];
        } else {
            uint4* dst = buf ? ax1 : ax0;
            const uint32_t* p = Hp + (size_t)(m0 >> 5) * E_ + k0 + quad * 8;
            dst[0] = *(const uint4*)p;
            dst[1] = *(const uint4*)(p + 4);
        }
    };
    auto loadB = [&](int k0, int buf) __attribute__((always_inline)) {
        bf16x8* dst = buf ? bf1 : bf0;
#pragma unroll
        for (int j = 0; j < 9; ++j)
            dst[j] = *(const bf16x8*)&Bp[(size_t)(j * 16 + l15) * K + k0 + quad * 8];
    };
    auto compute = [&](int buf) __attribute__((always_inline)) {
        bf16x8 a0, a1;
        if constexpr (MODE == 0) {
            const float* src = buf ? af1 : af0;
#pragma unroll
            for (int jj = 0; jj < 8; ++jj) {
                a0[jj] = (short)bf16_rne(src[jj]);
                a1[jj] = (short)bf16_rne(src[8 + jj]);
            }
        } else if constexpr (MODE == 1) {
            const uint32_t* src = buf ? aw1_ : aw0;
            const int base = quad * 8;
#pragma unroll
            for (int jj = 0; jj < 8; ++jj) {
                a0[jj] = (short)(((src[0] >> (base + jj)) & 1u) ? 0x3F80 : 0);
                a1[jj] = (short)(((src[1] >> (base + jj)) & 1u) ? 0x3F80 : 0);
            }
        } else {
            const uint4* src = buf ? ax1 : ax0;
            const uint32_t u[8] = {src[0].x, src[0].y, src[0].z, src[0].w,
                                   src[1].x, src[1].y, src[1].z, src[1].w};
#pragma unroll
            for (int jj = 0; jj < 8; ++jj) {
                a0[jj] = (short)(((u[jj] >> l15) & 1u) ? 0x3F80 : 0);
                a1[jj] = (short)(((u[jj] >> (16 + l15)) & 1u) ? 0x3F80 : 0);
            }
        }
        const bf16x8* bsrc = buf ? bf1 : bf0;
#pragma unroll
        for (int j = 0; j < 9; ++j) {
            acc[j]     = __builtin_amdgcn_mfma_f32_16x16x32_bf16(a0, bsrc[j], acc[j],     0, 0, 0);
            acc[9 + j] = __builtin_amdgcn_mfma_f32_16x16x32_bf16(a1, bsrc[j], acc[9 + j], 0, 0, 0);
        }
    };

    loadA(kwv, 0); loadB(kwv, 0);
#pragma unroll 1
    for (int s = 0; s < SW; s += 2) {
        if (s + 1 < SW) { loadA(kwv + (s + 1) * KT, 1); loadB(kwv + (s + 1) * KT, 1); }
        compute(0);
        if (s + 1 < SW) {
            if (s + 2 < SW) { loadA(kwv + (s + 2) * KT, 0); loadB(kwv + (s + 2) * KT, 0); }
            compute(1);
        }
    }

    // ---- cross-wave K reduction (3 barriers) ----
    auto stR = [&](int base) __attribute__((always_inline)) {
#pragma unroll
        for (int g = 0; g < 2; ++g)
#pragma unroll
            for (int j = 0; j < 9; ++j)
#pragma unroll
                for (int r = 0; r < 4; ++r)
                    R[base + (g * 16 + quad * 4 + r) * LRF + j * 16 + l15] = acc[g * 9 + j][r];
    };
    auto ldR = [&](int base) __attribute__((always_inline)) {
#pragma unroll
        for (int g = 0; g < 2; ++g)
#pragma unroll
            for (int j = 0; j < 9; ++j)
#pragma unroll
                for (int r = 0; r < 4; ++r)
                    acc[g * 9 + j][r] += R[base + (g * 16 + quad * 4 + r) * LRF + j * 16 + l15];
    };
    if (wave == 1) stR(0);
    if (wave == 3) stR(32 * LRF);
    __syncthreads();
    if (wave == 0) ldR(0);
    if (wave == 2) ldR(32 * LRF);
    __syncthreads();
    if (wave == 2) stR(0);
    __syncthreads();

    if (wave == 0) {
        ldR(0);
        float mul[2][4];
        if constexpr (MODE != 0) {
#pragma unroll
            for (int g = 0; g < 2; ++g)
#pragma unroll
                for (int r = 0; r < 4; ++r) {
                    float sv = __shfl(acc[g * 9 + 8][r], lane & 48);  // col 128 holder in quad
                    mul[g][r] = (sv > 0.f) ? 1.f / sv : 0.f;
                }
        }
#pragma unroll
        for (int g = 0; g < 2; ++g) {
            const int row = m0 + g * 16 + quad * 4;
            if constexpr (MODE == 2) {
                float* op = outF + ((size_t)batch * N_ + row) * C_;
#pragma unroll
                for (int j = 0; j < 8; ++j) {
                    int c = j * 16 + l15;
#pragma unroll
                    for (int r = 0; r < 4; ++r) op[(size_t)r * C_ + c] = acc[g * 9 + j][r] * mul[g][r];
                }
            } else {
#pragma unroll
                for (int j = 0; j < 8; ++j) {
                    int c = j * 16 + l15;
                    float v0, v1, v2, v3;
                    if constexpr (MODE == 0) {
                        float bb = bias[c];
                        v0 = acc[g * 9 + j][0] + bb; v1 = acc[g * 9 + j][1] + bb;
                        v2 = acc[g * 9 + j][2] + bb; v3 = acc[g * 9 + j][3] + bb;
                    } else {
                        v0 = acc[g * 9 + j][0] * mul[g][0]; v1 = acc[g * 9 + j][1] * mul[g][1];
                        v2 = acc[g * 9 + j][2] * mul[g][2]; v3 = acc[g * 9 + j][3] * mul[g][3];
                    }
                    uint32_t q0 = (uint32_t)bf16_rne(v0) | ((uint32_t)bf16_rne(v1) << 16);
                    uint32_t q1 = (uint32_t)bf16_rne(v2) | ((uint32_t)bf16_rne(v3) << 16);
                    uint16_t* op = outT + ((size_t)batch * CN + c) * OLD + row;
                    *(uint2*)op = make_uint2(q0, q1);
                }
            }
        }
    }
    __syncthreads();   // protect R before this group's next virtual block
}

// ---------------------------------------------------------------------------
// Fused cooperative kernel: 256 blocks x 512 thr (two 4-wave groups/block).
// phases: [pack + prep] sync [fc] sync [v2e] sync [e2v]
// ---------------------------------------------------------------------------
__global__ __launch_bounds__(512, 2)
void fused_k(const float* __restrict__ x, const float* __restrict__ H,
             const float* __restrict__ W, const float* __restrict__ bias,
             float* __restrict__ out, uint32_t* __restrict__ HT,
             uint16_t* __restrict__ WTb, uint16_t* __restrict__ ebfT) {
    __shared__ float R[2 * GR];                  // 74 KB: one region per wave-group
    cg::grid_group grid = cg::this_grid();
    const int g  = threadIdx.x >> 8;             // wave-group 0/1
    const int tg = threadIdx.x & 255;
    uint16_t* xwbT = (uint16_t*)out;             // d_out is dead scratch until e2v

    // ---- phase 1: pack H -> HT bits, + prep (WTb, ones rows) ----
    {
        const int nth = gridDim.x * blockDim.x;  // 131072
        const int tid = blockIdx.x * blockDim.x + threadIdx.x;
        for (int w = tid; w < (int)HT_E; w += nth) {
            const int e  = w & (E_ - 1);
            const int ng = (w >> 11) & 127;
            const int b  = w >> 18;
            const float* hp = H + ((size_t)b * N_ + ng * 32) * E_ + e;
            uint32_t v = 0;
#pragma unroll
            for (int i = 0; i < 32; ++i) v |= (hp[(size_t)i * E_] > 0.5f) ? (1u << i) : 0u;
            HT[w] = v;
        }
        const int NW = (int)WT_E;                // 18432
        const int NX = B_ * 16 * (N_ / 2);       // 262144
        const int NE = B_ * 16 * (E_ / 2);       // 131072
        uint32_t* xw32 = (uint32_t*)xwbT;
        uint32_t* eb32 = (uint32_t*)ebfT;
        for (int i = tid; i < NW + NX + NE; i += nth) {
            if (i < NW) {
                int c = i >> 7, k = i & 127;
                WTb[i] = bf16_rne((c < C_) ? W[k * C_ + c] : 0.f);
            } else if (i < NW + NX) {
                int j = i - NW;
                int b = j >> 15, rr = j & 32767;
                int r = rr >> 11, n2 = rr & 2047;
                xw32[((size_t)b * CN + (C_ + r)) * (N_ / 2) + n2] = (r == 0) ? 0x3F803F80u : 0u;
            } else {
                int j = i - NW - NX;
                int b = j >> 14, rr = j & 16383;
                int r = rr >> 10, e2 = rr & 1023;
                eb32[((size_t)b * CN + (C_ + r)) * (E_ / 2) + e2] = (r == 0) ? 0x3F803F80u : 0u;
            }
        }
    }
    __threadfence();
    grid.sync();

    // ---- phase 2: fc (1024 virtual blocks) ----
#pragma unroll 1
    for (int it = 0; it < 2; ++it)
        gemm_block<0>(blockIdx.x * 2 + g + it * 512, tg, R + g * GR,
                      x, nullptr, WTb, bias, xwbT, nullptr);
    __threadfence();
    grid.sync();

    // ---- phase 3: v2e (512 virtual blocks) ----
    gemm_block<1>(blockIdx.x * 2 + g, tg, R + g * GR,
                  nullptr, HT, xwbT, nullptr, ebfT, nullptr);
    __threadfence();
    grid.sync();

    // ---- phase 4: e2v (1024 virtual blocks) ----
#pragma unroll 1
    for (int it = 0; it < 2; ++it)
        gemm_block<2>(blockIdx.x * 2 + g + it * 512, tg, R + g * GR,
                      nullptr, HT, ebfT, nullptr, nullptr, out);
}

// ---------------------------------------------------------------------------
extern "C" void kernel_launch(void* const* d_in, const int* in_sizes, int n_in,
                              void* d_out, int out_size, void* d_ws, size_t ws_size,
                              hipStream_t stream) {
    const float* x    = (const float*)d_in[0];   // [8,4096,128]
    const float* H    = (const float*)d_in[1];   // [8,4096,2048]
    const float* W    = (const float*)d_in[2];   // [128,128]
    const float* bias = (const float*)d_in[3];   // [128]
    float* out = (float*)d_out;                  // [8,4096,128]

    // ws (~12.8 MB): HT (8 MB) | WTb (36 KB) | ebfT (4.7 MB)
    uint32_t* HT   = (uint32_t*)d_ws;
    uint16_t* WTb  = (uint16_t*)(HT + HT_E);
    uint16_t* ebfT = WTb + WT_E;

    void* args[8] = {(void*)&x, (void*)&H, (void*)&W, (void*)&bias,
                     (void*)&out, (void*)&HT, (void*)&WTb, (void*)&ebfT};
    hipLaunchCooperativeKernel((void*)fused_k, dim3(256), dim3(512), args, 0, stream);
}